// Round 9
// baseline (277.967 us; speedup 1.0000x reference)
//
#include <hip/hip_runtime.h>
#include <hip/hip_fp16.h>
#include <hip/hip_fp8.h>
#include <stdint.h>

#define D 128
#define GT 16       // nodes per wave-tile in the pool GEMM
#define SLOTS 48    // ELL width; avg in-degree = 16, 8 sigma tail
#define EPB 4096    // edges per partition block
#define PTB 1024    // partition block threads
#define CAPE 5120   // edge-bucket capacity (mean 4092, 16 sigma)
#define MAXB 400    // >= NBK = ceil(n/256) = 391
#define MAXDATE 8192
#define WPN 16384   // halves per W-part (hi at [0,WPN), lo at [WPN,2*WPN))
#define PWAVES 8    // waves per pool-GEMM block

typedef _Float16 f16x8 __attribute__((ext_vector_type(8)));
typedef float    f32x4 __attribute__((ext_vector_type(4)));
typedef float    f32x2 __attribute__((ext_vector_type(2)));

// ---------------- pack W0 (fp16 hi+lo) + date bitmap + zero flag/cursors/state --------------
// Date bitmap (12.5 KB, L1-resident) lets partition flag h1-needed sources inline,
// eliminating mark_kernel and its dependency chain (mark <- list <- norm <- build).
__global__ __launch_bounds__(256) void wpack_kernel(const float* __restrict__ W,
                                                    _Float16* __restrict__ wp,
                                                    int* __restrict__ cursorAB,
                                                    float* __restrict__ pooled,
                                                    int* __restrict__ cnt,
                                                    const int* __restrict__ node_type,
                                                    unsigned int* __restrict__ bitmap,
                                                    int* __restrict__ flag32, int n) {
    int tid = threadIdx.x;
    int gt  = blockIdx.x * 256 + tid;
    int gsz = gridDim.x * 256;
    int lane = tid & 63;
    if (blockIdx.x == 0) {
        for (int i = tid; i < 2 * MAXB; i += 256) cursorAB[i] = 0;
        if (tid < D) pooled[tid] = 0.f;
        if (tid == 0) { cnt[0] = 0; cnt[1] = 0; }
    }
    // date bitmap via wave ballot (gsz multiple of 64, waves 64-aligned)
    int nround = (n + 63) & ~63;
    for (int v = gt; v < nround; v += gsz) {
        bool isd = false;
        if (v < n) {
            isd = (node_type[v * 3 + 0] == 0) && (node_type[v * 3 + 1] == 0) &&
                  (node_type[v * 3 + 2] == 1);
        }
        unsigned long long msk = __ballot(isd);
        if (lane == 0)  bitmap[v >> 5] = (unsigned int)msk;
        if (lane == 32) bitmap[v >> 5] = (unsigned int)(msk >> 32);
    }
    // zero flag (word stores)
    for (int i = gt; i < ((n + 3) >> 2); i += gsz) flag32[i] = 0;
    // pack W0
    for (int idx = gt; idx < WPN; idx += gsz) {
        int j = idx & 7;
        int l = (idx >> 3) & 63;
        int c = (idx >> 9) & 7;
        int k0b = idx >> 12;
        int q = l >> 4, r = l & 15;
        float w = W[(k0b * 32 + q * 8 + j) * 128 + c * 16 + r];
        _Float16 hi = (_Float16)w;
        wp[idx] = hi;
        wp[idx + WPN] = (_Float16)(w - (float)hi);
    }
}

// ---------------- K1: coarse partition; edges cached in registers across phases --------------
// Two-sided bucket scatter (round-5: direct ELL scatter = 8x write amp; round-6: cross-XCD
// global atomics = HBM RMWs). sbuf is BYTES (bucket id implied by region). NEW: flags
// h1-needed sources inline via the date bitmap (replaces mark_kernel; idempotent byte
// stores, ~80k edges).
__global__ __launch_bounds__(PTB) void partition_kernel(
    const int* __restrict__ src, const int* __restrict__ dst, const float* __restrict__ ew,
    int* __restrict__ cursorA, int* __restrict__ cursorB,
    int2* __restrict__ ebuf, unsigned char* __restrict__ sbuf,
    const unsigned int* __restrict__ bitmap, unsigned char* __restrict__ flag,
    int E, int nbk) {
    __shared__ int histA[MAXB], histB[MAXB], baseA[MAXB], baseB[MAXB];
    int tid = threadIdx.x;
    for (int i = tid; i < nbk; i += PTB) { histA[i] = 0; histB[i] = 0; }
    __syncthreads();
    int e0 = blockIdx.x * EPB;
    int dcache[EPB / PTB], scache[EPB / PTB];
    float wcache[EPB / PTB];
    unsigned int dmask = 0;
    #pragma unroll
    for (int i = 0; i < EPB / PTB; ++i) {
        int e = e0 + i * PTB + tid;
        bool ok = e < E;
        dcache[i] = ok ? dst[e] : -1;
        scache[i] = ok ? src[e] : 0;
        wcache[i] = ok ? ew[e] : 0.f;
        if (ok) {
            atomicAdd(&histA[dcache[i] >> 8], 1);
            atomicAdd(&histB[scache[i] >> 8], 1);
            if ((bitmap[dcache[i] >> 5] >> (dcache[i] & 31)) & 1) dmask |= 1u << i;
        }
    }
    __syncthreads();
    for (int i = tid; i < nbk; i += PTB) {
        baseA[i] = atomicAdd(&cursorA[i], histA[i]);
        baseB[i] = atomicAdd(&cursorB[i], histB[i]);
        histA[i] = 0; histB[i] = 0;
    }
    __syncthreads();
    #pragma unroll
    for (int i = 0; i < EPB / PTB; ++i) {
        if (dcache[i] >= 0) {
            int d = dcache[i], s = scache[i];
            int bA = d >> 8;
            int pA = baseA[bA] + atomicAdd(&histA[bA], 1);
            if (pA < CAPE) ebuf[(size_t)bA * CAPE + pA] =
                make_int2(s | ((d & 255) << 17), __float_as_int(wcache[i]));
            int bB = s >> 8;
            int pB = baseB[bB] + atomicAdd(&histB[bB], 1);
            if (pB < CAPE) sbuf[(size_t)bB * CAPE + pB] = (unsigned char)(s & 255);
            if ((dmask >> i) & 1) flag[s] = 1;   // s feeds a date node's layer-2 gather
        }
    }
}

// ---------------- K2 merged: blocks [0,nbk) build ELL + deg_in; [nbk,2nbk) count deg_out -----
__global__ __launch_bounds__(256) void build_count_kernel(
    const int2* __restrict__ ebuf, const int* __restrict__ cursorA,
    const unsigned char* __restrict__ sbuf, const int* __restrict__ cursorB,
    int2* __restrict__ ell, int* __restrict__ deg_in, int* __restrict__ deg_out,
    int n, int nbk) {
    __shared__ int lcur[256];
    int tid = threadIdx.x;
    lcur[tid] = 0;
    __syncthreads();
    if (blockIdx.x < (unsigned)nbk) {
        int b = blockIdx.x;
        int cntE = min(cursorA[b], CAPE);
        const int2* buf = ebuf + (size_t)b * CAPE;
        for (int i = tid; i < cntE; i += 256) {
            int2 r = buf[i];
            int s = r.x & 0x1FFFF;
            int dlow = (r.x >> 17) & 255;
            int slot = atomicAdd(&lcur[dlow], 1);
            int node = (b << 8) + dlow;
            if (slot < SLOTS) ell[(size_t)node * SLOTS + slot] = make_int2(s, r.y);
        }
        __syncthreads();
        int v = (b << 8) + tid;
        if (v < n) deg_in[v] = lcur[tid];
    } else {
        int b = blockIdx.x - nbk;
        int cntS = min(cursorB[b], CAPE);
        const unsigned char* buf = sbuf + (size_t)b * CAPE;
        const unsigned int* buf32 = (const unsigned int*)buf;
        int nw = cntS >> 2;
        for (int i = tid; i < nw; i += 256) {
            unsigned int wv = buf32[i];
            atomicAdd(&lcur[wv & 255], 1);
            atomicAdd(&lcur[(wv >> 8) & 255], 1);
            atomicAdd(&lcur[(wv >> 16) & 255], 1);
            atomicAdd(&lcur[wv >> 24], 1);
        }
        if (tid < (cntS & 3)) atomicAdd(&lcur[buf[(nw << 2) + tid]], 1);
        __syncthreads();
        int v = (b << 8) + tid;
        if (v < n) deg_out[v] = lcur[tid];
    }
}

// ---------------- norms + date list + flagged-node compaction (fused; flag from partition) ---
__global__ __launch_bounds__(256) void norm_compact_kernel(
    const int* __restrict__ deg_out, const int* __restrict__ deg_in,
    const unsigned int* __restrict__ bitmap, const unsigned char* __restrict__ flag,
    float* __restrict__ norm_src, float* __restrict__ norm_dst,
    int* __restrict__ list, int* __restrict__ cnt,
    int* __restrict__ list2, int* __restrict__ cnt2, int n) {
    int v = blockIdx.x * 256 + threadIdx.x;
    int lane = threadIdx.x & 63;
    bool inb = v < n;
    int di = 0;
    if (inb) {
        int d_o = max(deg_out[v], 1);
        di = deg_in[v];
        norm_src[v] = 1.0f / sqrtf((float)d_o);
        norm_dst[v] = 1.0f / sqrtf((float)max(di, 1));
        if ((bitmap[v >> 5] >> (v & 31)) & 1) {
            int idx = atomicAdd(cnt, 1);   // compiler wave-coalesces uniform increments
            list[idx] = v;
        }
    }
    bool f = inb && (flag[v] != 0);
    unsigned long long mask = __ballot(f);
    int base = 0;
    if (lane == 0 && mask) base = atomicAdd(cnt2, __popcll(mask));
    base = __shfl(base, 0);
    if (f) {
        int off = __builtin_amdgcn_mbcnt_hi((unsigned int)(mask >> 32),
                  __builtin_amdgcn_mbcnt_lo((unsigned int)mask, 0));
        list2[base + off] = v | (min(di, SLOTS) << 17);
    }
}

// ---------------- MFMA GEMM fused cast: P8 = fp8(( ns.X )fp16 @ (Whi + Wlo)) -----------------
// wp staged in LDS once per 512-thread block; swapped MFMA operands -> dword fp8 stores.
__global__ __launch_bounds__(512) void gemm_mfma_kernel(
    const float* __restrict__ X, const float* __restrict__ ns,
    const _Float16* __restrict__ wp, unsigned char* __restrict__ P8, int n) {
    __shared__ _Float16 wl[2 * WPN];   // 64 KB: hi at [0,WPN), lo at [WPN,2*WPN)
    int tid  = threadIdx.x;
    int lane = tid & 63;
    int wib  = tid >> 6;
    {
        const ulonglong2* src16 = (const ulonglong2*)wp;
        ulonglong2* dst16 = (ulonglong2*)wl;
        #pragma unroll
        for (int i = 0; i < (2 * WPN * 2) / (512 * 16); ++i)
            dst16[i * 512 + tid] = src16[i * 512 + tid];
    }
    __syncthreads();

    int q = lane >> 4, r = lane & 15;
    int row0 = blockIdx.x * 128 + wib * 16;
    if (row0 >= n) return;   // after the barrier: safe
    int ra = min(row0 + r, n - 1);
    float sa = ns[ra];

    float4 x[8];
    #pragma unroll
    for (int kb = 0; kb < 4; ++kb) {
        x[2 * kb]     = *(const float4*)&X[(size_t)ra * 128 + kb * 32 + q * 8];
        x[2 * kb + 1] = *(const float4*)&X[(size_t)ra * 128 + kb * 32 + q * 8 + 4];
    }
    f16x8 a[4];
    #pragma unroll
    for (int kb = 0; kb < 4; ++kb) {
        a[kb][0] = (_Float16)(x[2 * kb].x * sa);
        a[kb][1] = (_Float16)(x[2 * kb].y * sa);
        a[kb][2] = (_Float16)(x[2 * kb].z * sa);
        a[kb][3] = (_Float16)(x[2 * kb].w * sa);
        a[kb][4] = (_Float16)(x[2 * kb + 1].x * sa);
        a[kb][5] = (_Float16)(x[2 * kb + 1].y * sa);
        a[kb][6] = (_Float16)(x[2 * kb + 1].z * sa);
        a[kb][7] = (_Float16)(x[2 * kb + 1].w * sa);
    }

    f32x4 acc[8];
    #pragma unroll
    for (int c = 0; c < 8; ++c) acc[c] = (f32x4){0.f, 0.f, 0.f, 0.f};

    const _Float16* wb = wl + lane * 8;
    #pragma unroll
    for (int c = 0; c < 8; ++c) {
        #pragma unroll
        for (int kb = 0; kb < 4; ++kb) {
            f16x8 bh = *(const f16x8*)&wb[kb * 4096 + c * 512];
            f16x8 bl = *(const f16x8*)&wb[kb * 4096 + c * 512 + WPN];
            acc[c] = __builtin_amdgcn_mfma_f32_16x16x32_f16(bh, a[kb], acc[c], 0, 0, 0);
            acc[c] = __builtin_amdgcn_mfma_f32_16x16x32_f16(bl, a[kb], acc[c], 0, 0, 0);
        }
    }

    int row = row0 + r;
    if (row < n) {
        #pragma unroll
        for (int c = 0; c < 8; ++c) {
            int w0 = __builtin_amdgcn_cvt_pk_fp8_f32(acc[c][0], acc[c][1], 0, false);
            int w1 = __builtin_amdgcn_cvt_pk_fp8_f32(acc[c][2], acc[c][3], w0, true);
            *(unsigned int*)&P8[(size_t)row * 128 + c * 16 + q * 4] = (unsigned int)w1;
        }
    }
}

// ---------------- gather1 over fp8 P (compact flagged list): h1 = ns*relu(nd*sum + b0) -------
__global__ __launch_bounds__(256) void gather1_kernel(
    const unsigned char* __restrict__ P8, const int2* __restrict__ ell,
    const float* __restrict__ norm_src, const float* __restrict__ norm_dst,
    const float* __restrict__ bias, const int* __restrict__ list2,
    const int* __restrict__ cnt2, __half* __restrict__ h1) {
    int wave = (blockIdx.x * 256 + threadIdx.x) >> 6;
    int lane = threadIdx.x & 63;
    int nn = __builtin_amdgcn_readfirstlane(*cnt2);
    if (wave >= nn) return;
    int pk = __builtin_amdgcn_readfirstlane(list2[wave]);
    int v = pk & 0x1FFFF;
    int m = pk >> 17;
    int half = lane >> 5;
    int l32  = lane & 31;
    const int2* row = ell + (size_t)v * SLOTS;
    const unsigned int* P32 = (const unsigned int*)P8;
    float nd = norm_dst[v];
    float ns = norm_src[v];
    float4 acc = make_float4(0.f, 0.f, 0.f, 0.f);

    if (m <= 16) {
        int4 q[8];
        #pragma unroll
        for (int i = 0; i < 8; ++i) q[i] = *(const int4*)&row[2 * i];
        unsigned int r[8];
        float w[8];
        #pragma unroll
        for (int i = 0; i < 8; ++i) {
            bool ok = (2 * i + half) < m;
            int s = ok ? (half ? q[i].z : q[i].x) : 0;
            w[i] = ok ? __int_as_float(half ? q[i].w : q[i].y) : 0.f;
            r[i] = P32[(size_t)s * 32 + l32];
        }
        #pragma unroll
        for (int i = 0; i < 8; ++i) {
            f32x2 c0 = __builtin_amdgcn_cvt_pk_f32_fp8((int)r[i], false);
            f32x2 c1 = __builtin_amdgcn_cvt_pk_f32_fp8((int)r[i], true);
            acc.x = fmaf(w[i], c0[0], acc.x);
            acc.y = fmaf(w[i], c0[1], acc.y);
            acc.z = fmaf(w[i], c1[0], acc.z);
            acc.w = fmaf(w[i], c1[1], acc.w);
        }
    } else {
        int4 q[16];
        #pragma unroll
        for (int i = 0; i < 16; ++i) q[i] = *(const int4*)&row[2 * i];
        unsigned int r[16];
        float w[16];
        #pragma unroll
        for (int i = 0; i < 16; ++i) {
            bool ok = (2 * i + half) < m;
            int s = ok ? (half ? q[i].z : q[i].x) : 0;
            w[i] = ok ? __int_as_float(half ? q[i].w : q[i].y) : 0.f;
            r[i] = P32[(size_t)s * 32 + l32];
        }
        #pragma unroll
        for (int i = 0; i < 16; ++i) {
            f32x2 c0 = __builtin_amdgcn_cvt_pk_f32_fp8((int)r[i], false);
            f32x2 c1 = __builtin_amdgcn_cvt_pk_f32_fp8((int)r[i], true);
            acc.x = fmaf(w[i], c0[0], acc.x);
            acc.y = fmaf(w[i], c0[1], acc.y);
            acc.z = fmaf(w[i], c1[0], acc.z);
            acc.w = fmaf(w[i], c1[1], acc.w);
        }
        if (m > 32) {   // Poisson(16) tail, ~0.01% of nodes
            for (int e = 32; e < m; e += 4) {
                int4 qa = *(const int4*)&row[e];
                int4 qb = *(const int4*)&row[e + 2];
                int2 p0 = half ? make_int2(qa.z, qa.w) : make_int2(qa.x, qa.y);
                int2 p1 = half ? make_int2(qb.z, qb.w) : make_int2(qb.x, qb.y);
                bool v0 = (e + half) < m;
                bool v1 = (e + 2 + half) < m;
                int s0 = v0 ? p0.x : 0;
                int s1 = v1 ? p1.x : 0;
                unsigned int r0 = P32[(size_t)s0 * 32 + l32];
                unsigned int r1 = P32[(size_t)s1 * 32 + l32];
                float w0 = v0 ? __int_as_float(p0.y) : 0.f;
                float w1 = v1 ? __int_as_float(p1.y) : 0.f;
                f32x2 c0 = __builtin_amdgcn_cvt_pk_f32_fp8((int)r0, false);
                f32x2 c1 = __builtin_amdgcn_cvt_pk_f32_fp8((int)r0, true);
                f32x2 d0 = __builtin_amdgcn_cvt_pk_f32_fp8((int)r1, false);
                f32x2 d1 = __builtin_amdgcn_cvt_pk_f32_fp8((int)r1, true);
                acc.x = fmaf(w0, c0[0], acc.x); acc.x = fmaf(w1, d0[0], acc.x);
                acc.y = fmaf(w0, c0[1], acc.y); acc.y = fmaf(w1, d0[1], acc.y);
                acc.z = fmaf(w0, c1[0], acc.z); acc.z = fmaf(w1, d1[0], acc.z);
                acc.w = fmaf(w0, c1[1], acc.w); acc.w = fmaf(w1, d1[1], acc.w);
            }
        }
    }

    acc.x += __shfl_xor(acc.x, 32);
    acc.y += __shfl_xor(acc.y, 32);
    acc.z += __shfl_xor(acc.z, 32);
    acc.w += __shfl_xor(acc.w, 32);
    if (half == 0) {
        float4 b4 = ((const float4*)bias)[l32];
        float ra = fmaxf(fmaf(acc.x, nd, b4.x), 0.f) * ns;
        float rb = fmaxf(fmaf(acc.y, nd, b4.y), 0.f) * ns;
        float rc = fmaxf(fmaf(acc.z, nd, b4.z), 0.f) * ns;
        float rd = fmaxf(fmaf(acc.w, nd, b4.w), 0.f) * ns;
        __half2 h0 = __floats2half2_rn(ra, rb);
        __half2 h1v = __floats2half2_rn(rc, rd);
        uint2 u;
        u.x = *(unsigned int*)&h0;
        u.y = *(unsigned int*)&h1v;
        ((uint2*)h1)[(size_t)v * 32 + l32] = u;
    }
}

// ---------------- layer-2 gather (date list), adaptive window like gather1 ------------------
__global__ __launch_bounds__(256) void gather2_list_kernel(
    const __half* __restrict__ h, const int* __restrict__ deg_in,
    const int2* __restrict__ ell, const float* __restrict__ norm_dst,
    const int* __restrict__ list, const int* __restrict__ cnt,
    float* __restrict__ out) {
    int wave = (blockIdx.x * 256 + threadIdx.x) >> 6;
    int lane = threadIdx.x & 63;
    if (wave >= min(*cnt, MAXDATE)) return;
    int v = __builtin_amdgcn_readfirstlane(list[wave]);
    int half = lane >> 5;
    int l32  = lane & 31;
    const int2* row = ell + (size_t)v * SLOTS;
    int m = min(__builtin_amdgcn_readfirstlane(deg_in[v]), SLOTS);
    float4 acc = make_float4(0.f, 0.f, 0.f, 0.f);

    if (m <= 16) {
        int4 q[8];
        #pragma unroll
        for (int i = 0; i < 8; ++i) q[i] = *(const int4*)&row[2 * i];
        float2 r[8];
        float w[8];
        #pragma unroll
        for (int i = 0; i < 8; ++i) {
            bool ok = (2 * i + half) < m;
            int s = ok ? (half ? q[i].z : q[i].x) : 0;
            w[i] = ok ? __int_as_float(half ? q[i].w : q[i].y) : 0.f;
            r[i] = ((const float2*)h)[(size_t)s * 32 + l32];
        }
        #pragma unroll
        for (int i = 0; i < 8; ++i) {
            float2 a01 = __half22float2(*(const __half2*)&r[i].x);
            float2 a23 = __half22float2(*(const __half2*)&r[i].y);
            acc.x = fmaf(w[i], a01.x, acc.x);
            acc.y = fmaf(w[i], a01.y, acc.y);
            acc.z = fmaf(w[i], a23.x, acc.z);
            acc.w = fmaf(w[i], a23.y, acc.w);
        }
    } else {
        int4 q[16];
        #pragma unroll
        for (int i = 0; i < 16; ++i) q[i] = *(const int4*)&row[2 * i];
        float2 r[16];
        float w[16];
        #pragma unroll
        for (int i = 0; i < 16; ++i) {
            bool ok = (2 * i + half) < m;
            int s = ok ? (half ? q[i].z : q[i].x) : 0;
            w[i] = ok ? __int_as_float(half ? q[i].w : q[i].y) : 0.f;
            r[i] = ((const float2*)h)[(size_t)s * 32 + l32];
        }
        #pragma unroll
        for (int i = 0; i < 16; ++i) {
            float2 a01 = __half22float2(*(const __half2*)&r[i].x);
            float2 a23 = __half22float2(*(const __half2*)&r[i].y);
            acc.x = fmaf(w[i], a01.x, acc.x);
            acc.y = fmaf(w[i], a01.y, acc.y);
            acc.z = fmaf(w[i], a23.x, acc.z);
            acc.w = fmaf(w[i], a23.y, acc.w);
        }
        if (m > 32) {
            for (int e = 32; e < m; e += 4) {
                int4 qa = *(const int4*)&row[e];
                int4 qb = *(const int4*)&row[e + 2];
                int2 p0 = half ? make_int2(qa.z, qa.w) : make_int2(qa.x, qa.y);
                int2 p1 = half ? make_int2(qb.z, qb.w) : make_int2(qb.x, qb.y);
                bool v0 = (e + half) < m;
                bool v1 = (e + 2 + half) < m;
                int s0 = v0 ? p0.x : 0;
                int s1 = v1 ? p1.x : 0;
                float2 raw0 = ((const float2*)h)[(size_t)s0 * 32 + l32];
                float2 raw1 = ((const float2*)h)[(size_t)s1 * 32 + l32];
                float w0 = v0 ? __int_as_float(p0.y) : 0.f;
                float w1 = v1 ? __int_as_float(p1.y) : 0.f;
                float2 a01 = __half22float2(*(const __half2*)&raw0.x);
                float2 a23 = __half22float2(*(const __half2*)&raw0.y);
                float2 b01 = __half22float2(*(const __half2*)&raw1.x);
                float2 b23 = __half22float2(*(const __half2*)&raw1.y);
                acc.x = fmaf(w0, a01.x, acc.x); acc.x = fmaf(w1, b01.x, acc.x);
                acc.y = fmaf(w0, a01.y, acc.y); acc.y = fmaf(w1, b01.y, acc.y);
                acc.z = fmaf(w0, a23.x, acc.z); acc.z = fmaf(w1, b23.x, acc.z);
                acc.w = fmaf(w0, a23.y, acc.w); acc.w = fmaf(w1, b23.y, acc.w);
            }
        }
    }
    acc.x += __shfl_xor(acc.x, 32);
    acc.y += __shfl_xor(acc.y, 32);
    acc.z += __shfl_xor(acc.z, 32);
    acc.w += __shfl_xor(acc.w, 32);
    if (half == 0) {
        float nd = norm_dst[v];
        ((float4*)(out + (size_t)wave * D))[l32] =
            make_float4(acc.x * nd, acc.y * nd, acc.z * nd, acc.w * nd);
    }
}

// ---------------- GEMM + bias + relu + fused sum-pool, W1-stationary in LDS -----------------
__global__ __launch_bounds__(512) void gemm_pool_kernel(
    const float* __restrict__ X, const float* __restrict__ W,
    const float* __restrict__ bias, const int* __restrict__ cnt,
    float* __restrict__ pooled) {
    __shared__ float wlds[D * D];           // 64 KB
    __shared__ float rows[PWAVES][GT * D];  // 64 KB
    int tid  = threadIdx.x;
    int lane = tid & 63;
    int wib  = tid >> 6;

    const float4* W4 = (const float4*)W;
    for (int i = tid; i < (D * D) / 4; i += 512)
        *(float4*)&wlds[i * 4] = W4[i];
    __syncthreads();

    int m = min(*cnt, MAXDATE);
    int ntiles = (m + GT - 1) / GT;
    float2 bb = ((const float2*)bias)[lane];
    float psx = 0.f, psy = 0.f;
    bool any = false;
    float* rw = rows[wib];
    const float2* X2 = (const float2*)X;

    for (int tile = blockIdx.x * PWAVES + wib; tile < ntiles; tile += gridDim.x * PWAVES) {
        int t0 = tile * GT;
        any = true;
        #pragma unroll
        for (int t = 0; t < GT; ++t) {
            int i = t0 + t;
            float2 r = (i < m) ? X2[(size_t)i * 64 + lane] : make_float2(0.f, 0.f);
            *(float2*)&rw[t * D + 2 * lane] = r;
        }
        __builtin_amdgcn_wave_barrier();

        float2 acc[GT];
        #pragma unroll
        for (int t = 0; t < GT; ++t) acc[t] = make_float2(0.f, 0.f);

        for (int k = 0; k < D; k += 4) {
            float2 w0 = *(const float2*)&wlds[(k + 0) * D + 2 * lane];
            float2 w1 = *(const float2*)&wlds[(k + 1) * D + 2 * lane];
            float2 w2 = *(const float2*)&wlds[(k + 2) * D + 2 * lane];
            float2 w3 = *(const float2*)&wlds[(k + 3) * D + 2 * lane];
            #pragma unroll
            for (int t = 0; t < GT; ++t) {
                float4 r = *(const float4*)&rw[t * D + k];
                acc[t].x = fmaf(r.x, w0.x, acc[t].x); acc[t].y = fmaf(r.x, w0.y, acc[t].y);
                acc[t].x = fmaf(r.y, w1.x, acc[t].x); acc[t].y = fmaf(r.y, w1.y, acc[t].y);
                acc[t].x = fmaf(r.z, w2.x, acc[t].x); acc[t].y = fmaf(r.z, w2.y, acc[t].y);
                acc[t].x = fmaf(r.w, w3.x, acc[t].x); acc[t].y = fmaf(r.w, w3.y, acc[t].y);
            }
        }

        #pragma unroll
        for (int t = 0; t < GT; ++t) {
            if (t0 + t < m) {
                psx += fmaxf(acc[t].x + bb.x, 0.f);
                psy += fmaxf(acc[t].y + bb.y, 0.f);
            }
        }
        __builtin_amdgcn_wave_barrier();   // rows slab reused next grid-stride iter
    }

    if (any) {
        atomicAdd(&pooled[2 * lane + 0], psx);
        atomicAdd(&pooled[2 * lane + 1], psy);
    }
}

// ---------------- tiny MLP head ----------------
__global__ void mlp_kernel(const float* __restrict__ pooled, const int* __restrict__ cnt,
                           const float* __restrict__ w1, const float* __restrict__ b1,
                           const float* __restrict__ w2, const float* __restrict__ b2,
                           float* __restrict__ out) {
    __shared__ float hid[8];
    int t = threadIdx.x;
    float inv = 1.0f / (float)(*cnt);
    if (t < 8) {
        float a = b1[t];
        for (int k = 0; k < 128; ++k) a = fmaf(pooled[k] * inv, w1[k * 8 + t], a);
        hid[t] = fmaxf(a, 0.f);
    }
    __syncthreads();
    if (t < 16) {
        float a = b2[t];
        for (int j = 0; j < 8; ++j) a = fmaf(hid[j], w2[j * 16 + t], a);
        out[t] = a;
    }
}

extern "C" void kernel_launch(void* const* d_in, const int* in_sizes, int n_in,
                              void* d_out, int out_size, void* d_ws, size_t ws_size,
                              hipStream_t stream) {
    const float* feature   = (const float*)d_in[0];
    const float* ew        = (const float*)d_in[1];
    const int*   src       = (const int*)d_in[2];
    const int*   dst       = (const int*)d_in[3];
    const int*   node_type = (const int*)d_in[4];
    const float* W0        = (const float*)d_in[5];
    const float* b0        = (const float*)d_in[6];
    const float* W1        = (const float*)d_in[7];
    const float* b1        = (const float*)d_in[8];
    const float* mw1       = (const float*)d_in[9];
    const float* mb1       = (const float*)d_in[10];
    const float* mw2       = (const float*)d_in[11];
    const float* mb2       = (const float*)d_in[12];
    float* out = (float*)d_out;

    const int n = in_sizes[0] / D;   // 100000
    const int E = in_sizes[1];       // 1600000
    const int NBK = (n + 255) >> 8;  // 391

    // ---- workspace carve-up (aligned to 256B), ~99 MB ----
    char* ws = (char*)d_ws;
    size_t off = 0;
    auto alloc = [&](size_t bytes) -> void* {
        void* p = ws + off;
        off = (off + bytes + 255) & ~(size_t)255;
        return p;
    };
    int*           cursorAB = (int*)alloc(2 * MAXB * 4);
    int*           deg_in   = (int*)alloc((size_t)n * 4);
    int*           deg_out  = (int*)alloc((size_t)n * 4);
    float*         norm_src = (float*)alloc((size_t)n * 4);
    float*         norm_dst = (float*)alloc((size_t)n * 4);
    int*           list     = (int*)alloc((size_t)n * 4);
    int*           list2    = (int*)alloc((size_t)n * 4);
    unsigned char* flag     = (unsigned char*)alloc(((size_t)n + 255) & ~(size_t)255);
    unsigned int*  bitmap   = (unsigned int*)alloc((((size_t)n + 63) / 64 * 2 + 2) * 4);
    int2*          ell      = (int2*)alloc(((size_t)n * SLOTS + 8) * 8);  // 38.4 MB
    int2*          ebuf     = (int2*)alloc((size_t)NBK * CAPE * 8);       // 16 MB
    unsigned char* sbuf     = (unsigned char*)alloc((size_t)NBK * CAPE);  // 2 MB (bytes)
    unsigned char* P8       = (unsigned char*)alloc((size_t)n * D);       // 12.8 MB (fp8)
    __half*        h1       = (__half*)alloc((size_t)n * D * 2);          // 25.6 MB
    _Float16*      wp       = (_Float16*)alloc(2 * WPN * 2);              // 64 KB (hi+lo)
    float*         pooled   = (float*)alloc(D * 4);
    int*           cnt      = (int*)alloc(256);
    float*         agg      = (float*)ebuf;   // 4 MB, ebuf dead after build_count

    int* cursorA = cursorAB;
    int* cursorB = cursorAB + MAXB;
    int* cnt2    = cnt + 1;

    const int TB = 256;
    int pblk = (E + EPB - 1) / EPB;
    int nblk = (n + TB - 1) / TB;

    wpack_kernel<<<16, TB, 0, stream>>>(W0, wp, cursorAB, pooled, cnt,
                                        node_type, bitmap, (int*)flag, n);
    partition_kernel<<<pblk, PTB, 0, stream>>>(src, dst, ew, cursorA, cursorB,
                                               ebuf, sbuf, bitmap, flag, E, NBK);
    build_count_kernel<<<2 * NBK, TB, 0, stream>>>(ebuf, cursorA, sbuf, cursorB,
                                                   ell, deg_in, deg_out, n, NBK);
    norm_compact_kernel<<<nblk, TB, 0, stream>>>(deg_out, deg_in, bitmap, flag,
                                                 norm_src, norm_dst, list, cnt,
                                                 list2, cnt2, n);

    // P8 = fp8(( norm_src . X ) @ W0) via MFMA (wp LDS-staged, 512-thread blocks)
    gemm_mfma_kernel<<<(n + 127) / 128, 512, 0, stream>>>(feature, norm_src, wp, P8, n);

    // layer 1 aggregation over the compact flagged list + epilogue
    gather1_kernel<<<(n * 64 + TB - 1) / TB, TB, 0, stream>>>(
        P8, ell, norm_src, norm_dst, b0, list2, cnt2, h1);

    // layer 2: date nodes only
    gather2_list_kernel<<<(MAXDATE * 64) / TB, TB, 0, stream>>>(
        h1, deg_in, ell, norm_dst, list, cnt, agg);
    gemm_pool_kernel<<<64, 512, 0, stream>>>(agg, W1, b1, cnt, pooled);

    mlp_kernel<<<1, 64, 0, stream>>>(pooled, cnt, mw1, mb1, mw2, mb2, out);
}

// Round 10
// 269.606 us; speedup vs baseline: 1.0310x; 1.0310x over previous
//
#include <hip/hip_runtime.h>
#include <hip/hip_fp16.h>
#include <hip/hip_fp8.h>
#include <stdint.h>

#define D 128
#define GT 16       // nodes per wave-tile in the pool GEMM
#define SLOTS 48    // ELL width; avg in-degree = 16, 8 sigma tail
#define EPB 4096    // edges per partition block
#define PTB 1024    // partition block threads
#define CAPE 5120   // edge-bucket capacity (mean 4092, 16 sigma)
#define MAXB 400    // >= NBK = ceil(n/256) = 391
#define MAXDATE 8192
#define WPN 16384   // halves per W-part (hi at [0,WPN), lo at [WPN,2*WPN))
#define PWAVES 8    // waves per pool-GEMM block

typedef _Float16 f16x8 __attribute__((ext_vector_type(8)));
typedef float    f32x4 __attribute__((ext_vector_type(4)));
typedef float    f32x2 __attribute__((ext_vector_type(2)));

// ---------------- K1: coarse partition; edges cached in registers across phases --------------
// Two-sided bucket scatter (round-5: direct ELL scatter = 8x write amp; round-6: cross-XCD
// global atomics = HBM RMWs; round-9: per-edge bitmap test + inline flag stores in the hot
// loop cost more than the 3us mark_kernel they replaced). sbuf is BYTES (bucket id implied
// by region).
__global__ __launch_bounds__(PTB) void partition_kernel(
    const int* __restrict__ src, const int* __restrict__ dst, const float* __restrict__ ew,
    int* __restrict__ cursorA, int* __restrict__ cursorB,
    int2* __restrict__ ebuf, unsigned char* __restrict__ sbuf, int E, int nbk) {
    __shared__ int histA[MAXB], histB[MAXB], baseA[MAXB], baseB[MAXB];
    int tid = threadIdx.x;
    for (int i = tid; i < nbk; i += PTB) { histA[i] = 0; histB[i] = 0; }
    __syncthreads();
    int e0 = blockIdx.x * EPB;
    int dcache[EPB / PTB], scache[EPB / PTB];
    float wcache[EPB / PTB];
    #pragma unroll
    for (int i = 0; i < EPB / PTB; ++i) {
        int e = e0 + i * PTB + tid;
        bool ok = e < E;
        dcache[i] = ok ? dst[e] : -1;
        scache[i] = ok ? src[e] : 0;
        wcache[i] = ok ? ew[e] : 0.f;
        if (ok) {
            atomicAdd(&histA[dcache[i] >> 8], 1);
            atomicAdd(&histB[scache[i] >> 8], 1);
        }
    }
    __syncthreads();
    for (int i = tid; i < nbk; i += PTB) {
        baseA[i] = atomicAdd(&cursorA[i], histA[i]);
        baseB[i] = atomicAdd(&cursorB[i], histB[i]);
        histA[i] = 0; histB[i] = 0;
    }
    __syncthreads();
    #pragma unroll
    for (int i = 0; i < EPB / PTB; ++i) {
        if (dcache[i] >= 0) {
            int d = dcache[i], s = scache[i];
            int bA = d >> 8;
            int pA = baseA[bA] + atomicAdd(&histA[bA], 1);
            if (pA < CAPE) ebuf[(size_t)bA * CAPE + pA] =
                make_int2(s | ((d & 255) << 17), __float_as_int(wcache[i]));
            int bB = s >> 8;
            int pB = baseB[bB] + atomicAdd(&histB[bB], 1);
            if (pB < CAPE) sbuf[(size_t)bB * CAPE + pB] = (unsigned char)(s & 255);
        }
    }
}

// ---------------- K2 merged: blocks [0,nbk) build ELL + deg_in; [nbk,2nbk) count deg_out -----
__global__ __launch_bounds__(256) void build_count_kernel(
    const int2* __restrict__ ebuf, const int* __restrict__ cursorA,
    const unsigned char* __restrict__ sbuf, const int* __restrict__ cursorB,
    int2* __restrict__ ell, int* __restrict__ deg_in, int* __restrict__ deg_out,
    int n, int nbk) {
    __shared__ int lcur[256];
    int tid = threadIdx.x;
    lcur[tid] = 0;
    __syncthreads();
    if (blockIdx.x < (unsigned)nbk) {
        int b = blockIdx.x;
        int cntE = min(cursorA[b], CAPE);
        const int2* buf = ebuf + (size_t)b * CAPE;
        for (int i = tid; i < cntE; i += 256) {
            int2 r = buf[i];
            int s = r.x & 0x1FFFF;
            int dlow = (r.x >> 17) & 255;
            int slot = atomicAdd(&lcur[dlow], 1);
            int node = (b << 8) + dlow;
            if (slot < SLOTS) ell[(size_t)node * SLOTS + slot] = make_int2(s, r.y);
        }
        __syncthreads();
        int v = (b << 8) + tid;
        if (v < n) deg_in[v] = lcur[tid];
    } else {
        int b = blockIdx.x - nbk;
        int cntS = min(cursorB[b], CAPE);
        const unsigned char* buf = sbuf + (size_t)b * CAPE;
        const unsigned int* buf32 = (const unsigned int*)buf;
        int nw = cntS >> 2;
        for (int i = tid; i < nw; i += 256) {
            unsigned int wv = buf32[i];
            atomicAdd(&lcur[wv & 255], 1);
            atomicAdd(&lcur[(wv >> 8) & 255], 1);
            atomicAdd(&lcur[(wv >> 16) & 255], 1);
            atomicAdd(&lcur[wv >> 24], 1);
        }
        if (tid < (cntS & 3)) atomicAdd(&lcur[buf[(nw << 2) + tid]], 1);
        __syncthreads();
        int v = (b << 8) + tid;
        if (v < n) deg_out[v] = lcur[tid];
    }
}

// ---------------- norms + date-node compact list + zero h1-needed flag ----------------------
__global__ void norm_flag_kernel(const int* __restrict__ deg_out, const int* __restrict__ deg_in,
                                 const int* __restrict__ node_type,
                                 float* __restrict__ norm_src, float* __restrict__ norm_dst,
                                 int* __restrict__ list, int* __restrict__ cnt,
                                 unsigned char* __restrict__ flag, int n) {
    int v = blockIdx.x * blockDim.x + threadIdx.x;
    if (v < n) {
        float d_o = (float)max(deg_out[v], 1);
        float d_i = (float)max(deg_in[v], 1);
        norm_src[v] = 1.0f / sqrtf(d_o);
        norm_dst[v] = 1.0f / sqrtf(d_i);
        flag[v] = 0;
        int t0 = node_type[v * 3 + 0];
        int t1 = node_type[v * 3 + 1];
        int t2 = node_type[v * 3 + 2];
        if (t0 == 0 && t1 == 0 && t2 == 1) {
            int idx = atomicAdd(cnt, 1);
            list[idx] = v;
        }
    }
}

// ---------------- mark srcs of date-node in-edges: only these need h1 -----------------------
__global__ __launch_bounds__(256) void mark_kernel(
    const int* __restrict__ list, const int* __restrict__ cnt,
    const int2* __restrict__ ell, const int* __restrict__ deg_in,
    unsigned char* __restrict__ flag) {
    int wave = (blockIdx.x * 256 + threadIdx.x) >> 6;
    int lane = threadIdx.x & 63;
    if (wave >= min(*cnt, MAXDATE)) return;
    int v = __builtin_amdgcn_readfirstlane(list[wave]);
    int m = min(deg_in[v], SLOTS);
    if (lane < m) {
        int s = ell[(size_t)v * SLOTS + lane].x;
        flag[s] = 1;
    }
}

// ---------------- compact flagged nodes into list2 (wave-aggregated atomics) ----------------
__global__ __launch_bounds__(256) void compact_kernel(
    const unsigned char* __restrict__ flag, const int* __restrict__ deg_in,
    int* __restrict__ list2, int* __restrict__ cnt2, int n) {
    int v = blockIdx.x * 256 + threadIdx.x;
    int lane = threadIdx.x & 63;
    bool f = (v < n) && (flag[v] != 0);
    unsigned long long mask = __ballot(f);
    int base = 0;
    if (lane == 0 && mask) base = atomicAdd(cnt2, __popcll(mask));
    base = __shfl(base, 0);
    if (f) {
        int off = __builtin_amdgcn_mbcnt_hi((unsigned int)(mask >> 32),
                  __builtin_amdgcn_mbcnt_lo((unsigned int)mask, 0));
        list2[base + off] = v | (min(deg_in[v], SLOTS) << 17);
    }
}

// ---------------- pack W0 (fp16 hi+lo) + zero cursors & small state (block 0) ----------------
__global__ __launch_bounds__(256) void wpack_kernel(const float* __restrict__ W,
                                                    _Float16* __restrict__ wp,
                                                    int* __restrict__ cursorAB,
                                                    float* __restrict__ pooled,
                                                    int* __restrict__ cnt) {
    int tid = threadIdx.x;
    if (blockIdx.x == 0) {
        for (int i = tid; i < 2 * MAXB; i += 256) cursorAB[i] = 0;
        if (tid < D) pooled[tid] = 0.f;
        if (tid == 0) { cnt[0] = 0; cnt[1] = 0; }
    }
    int base = blockIdx.x * 256 + tid;
    for (int idx = base; idx < WPN; idx += gridDim.x * 256) {
        int j = idx & 7;
        int l = (idx >> 3) & 63;
        int c = (idx >> 9) & 7;
        int k0b = idx >> 12;
        int q = l >> 4, r = l & 15;
        float w = W[(k0b * 32 + q * 8 + j) * 128 + c * 16 + r];
        _Float16 hi = (_Float16)w;
        wp[idx] = hi;
        wp[idx + WPN] = (_Float16)(w - (float)hi);
    }
}

// ---------------- MFMA GEMM fused cast: P8 = fp8(( ns.X )fp16 @ (Whi + Wlo)) -----------------
// wp staged in LDS once per 512-thread block; swapped MFMA operands -> dword fp8 stores.
__global__ __launch_bounds__(512) void gemm_mfma_kernel(
    const float* __restrict__ X, const float* __restrict__ ns,
    const _Float16* __restrict__ wp, unsigned char* __restrict__ P8, int n) {
    __shared__ _Float16 wl[2 * WPN];   // 64 KB: hi at [0,WPN), lo at [WPN,2*WPN)
    int tid  = threadIdx.x;
    int lane = tid & 63;
    int wib  = tid >> 6;
    {
        const ulonglong2* src16 = (const ulonglong2*)wp;
        ulonglong2* dst16 = (ulonglong2*)wl;
        #pragma unroll
        for (int i = 0; i < (2 * WPN * 2) / (512 * 16); ++i)
            dst16[i * 512 + tid] = src16[i * 512 + tid];
    }
    __syncthreads();

    int q = lane >> 4, r = lane & 15;
    int row0 = blockIdx.x * 128 + wib * 16;
    if (row0 >= n) return;   // after the barrier: safe
    int ra = min(row0 + r, n - 1);
    float sa = ns[ra];

    float4 x[8];
    #pragma unroll
    for (int kb = 0; kb < 4; ++kb) {
        x[2 * kb]     = *(const float4*)&X[(size_t)ra * 128 + kb * 32 + q * 8];
        x[2 * kb + 1] = *(const float4*)&X[(size_t)ra * 128 + kb * 32 + q * 8 + 4];
    }
    f16x8 a[4];
    #pragma unroll
    for (int kb = 0; kb < 4; ++kb) {
        a[kb][0] = (_Float16)(x[2 * kb].x * sa);
        a[kb][1] = (_Float16)(x[2 * kb].y * sa);
        a[kb][2] = (_Float16)(x[2 * kb].z * sa);
        a[kb][3] = (_Float16)(x[2 * kb].w * sa);
        a[kb][4] = (_Float16)(x[2 * kb + 1].x * sa);
        a[kb][5] = (_Float16)(x[2 * kb + 1].y * sa);
        a[kb][6] = (_Float16)(x[2 * kb + 1].z * sa);
        a[kb][7] = (_Float16)(x[2 * kb + 1].w * sa);
    }

    f32x4 acc[8];
    #pragma unroll
    for (int c = 0; c < 8; ++c) acc[c] = (f32x4){0.f, 0.f, 0.f, 0.f};

    const _Float16* wb = wl + lane * 8;
    #pragma unroll
    for (int c = 0; c < 8; ++c) {
        #pragma unroll
        for (int kb = 0; kb < 4; ++kb) {
            f16x8 bh = *(const f16x8*)&wb[kb * 4096 + c * 512];
            f16x8 bl = *(const f16x8*)&wb[kb * 4096 + c * 512 + WPN];
            acc[c] = __builtin_amdgcn_mfma_f32_16x16x32_f16(bh, a[kb], acc[c], 0, 0, 0);
            acc[c] = __builtin_amdgcn_mfma_f32_16x16x32_f16(bl, a[kb], acc[c], 0, 0, 0);
        }
    }

    int row = row0 + r;
    if (row < n) {
        #pragma unroll
        for (int c = 0; c < 8; ++c) {
            int w0 = __builtin_amdgcn_cvt_pk_fp8_f32(acc[c][0], acc[c][1], 0, false);
            int w1 = __builtin_amdgcn_cvt_pk_fp8_f32(acc[c][2], acc[c][3], w0, true);
            *(unsigned int*)&P8[(size_t)row * 128 + c * 16 + q * 4] = (unsigned int)w1;
        }
    }
}

// ---------------- gather1 over fp8 P (compact flagged list): h1 = ns*relu(nd*sum + b0) -------
__global__ __launch_bounds__(256) void gather1_kernel(
    const unsigned char* __restrict__ P8, const int2* __restrict__ ell,
    const float* __restrict__ norm_src, const float* __restrict__ norm_dst,
    const float* __restrict__ bias, const int* __restrict__ list2,
    const int* __restrict__ cnt2, __half* __restrict__ h1) {
    int wave = (blockIdx.x * 256 + threadIdx.x) >> 6;
    int lane = threadIdx.x & 63;
    int nn = __builtin_amdgcn_readfirstlane(*cnt2);
    if (wave >= nn) return;
    int pk = __builtin_amdgcn_readfirstlane(list2[wave]);
    int v = pk & 0x1FFFF;
    int m = pk >> 17;
    int half = lane >> 5;
    int l32  = lane & 31;
    const int2* row = ell + (size_t)v * SLOTS;
    const unsigned int* P32 = (const unsigned int*)P8;
    float nd = norm_dst[v];
    float ns = norm_src[v];
    float4 acc = make_float4(0.f, 0.f, 0.f, 0.f);

    if (m <= 16) {
        int4 q[8];
        #pragma unroll
        for (int i = 0; i < 8; ++i) q[i] = *(const int4*)&row[2 * i];
        unsigned int r[8];
        float w[8];
        #pragma unroll
        for (int i = 0; i < 8; ++i) {
            bool ok = (2 * i + half) < m;
            int s = ok ? (half ? q[i].z : q[i].x) : 0;
            w[i] = ok ? __int_as_float(half ? q[i].w : q[i].y) : 0.f;
            r[i] = P32[(size_t)s * 32 + l32];
        }
        #pragma unroll
        for (int i = 0; i < 8; ++i) {
            f32x2 c0 = __builtin_amdgcn_cvt_pk_f32_fp8((int)r[i], false);
            f32x2 c1 = __builtin_amdgcn_cvt_pk_f32_fp8((int)r[i], true);
            acc.x = fmaf(w[i], c0[0], acc.x);
            acc.y = fmaf(w[i], c0[1], acc.y);
            acc.z = fmaf(w[i], c1[0], acc.z);
            acc.w = fmaf(w[i], c1[1], acc.w);
        }
    } else {
        int4 q[16];
        #pragma unroll
        for (int i = 0; i < 16; ++i) q[i] = *(const int4*)&row[2 * i];
        unsigned int r[16];
        float w[16];
        #pragma unroll
        for (int i = 0; i < 16; ++i) {
            bool ok = (2 * i + half) < m;
            int s = ok ? (half ? q[i].z : q[i].x) : 0;
            w[i] = ok ? __int_as_float(half ? q[i].w : q[i].y) : 0.f;
            r[i] = P32[(size_t)s * 32 + l32];
        }
        #pragma unroll
        for (int i = 0; i < 16; ++i) {
            f32x2 c0 = __builtin_amdgcn_cvt_pk_f32_fp8((int)r[i], false);
            f32x2 c1 = __builtin_amdgcn_cvt_pk_f32_fp8((int)r[i], true);
            acc.x = fmaf(w[i], c0[0], acc.x);
            acc.y = fmaf(w[i], c0[1], acc.y);
            acc.z = fmaf(w[i], c1[0], acc.z);
            acc.w = fmaf(w[i], c1[1], acc.w);
        }
        if (m > 32) {   // Poisson(16) tail, ~0.01% of nodes
            for (int e = 32; e < m; e += 4) {
                int4 qa = *(const int4*)&row[e];
                int4 qb = *(const int4*)&row[e + 2];
                int2 p0 = half ? make_int2(qa.z, qa.w) : make_int2(qa.x, qa.y);
                int2 p1 = half ? make_int2(qb.z, qb.w) : make_int2(qb.x, qb.y);
                bool v0 = (e + half) < m;
                bool v1 = (e + 2 + half) < m;
                int s0 = v0 ? p0.x : 0;
                int s1 = v1 ? p1.x : 0;
                unsigned int r0 = P32[(size_t)s0 * 32 + l32];
                unsigned int r1 = P32[(size_t)s1 * 32 + l32];
                float w0 = v0 ? __int_as_float(p0.y) : 0.f;
                float w1 = v1 ? __int_as_float(p1.y) : 0.f;
                f32x2 c0 = __builtin_amdgcn_cvt_pk_f32_fp8((int)r0, false);
                f32x2 c1 = __builtin_amdgcn_cvt_pk_f32_fp8((int)r0, true);
                f32x2 d0 = __builtin_amdgcn_cvt_pk_f32_fp8((int)r1, false);
                f32x2 d1 = __builtin_amdgcn_cvt_pk_f32_fp8((int)r1, true);
                acc.x = fmaf(w0, c0[0], acc.x); acc.x = fmaf(w1, d0[0], acc.x);
                acc.y = fmaf(w0, c0[1], acc.y); acc.y = fmaf(w1, d0[1], acc.y);
                acc.z = fmaf(w0, c1[0], acc.z); acc.z = fmaf(w1, d1[0], acc.z);
                acc.w = fmaf(w0, c1[1], acc.w); acc.w = fmaf(w1, d1[1], acc.w);
            }
        }
    }

    acc.x += __shfl_xor(acc.x, 32);
    acc.y += __shfl_xor(acc.y, 32);
    acc.z += __shfl_xor(acc.z, 32);
    acc.w += __shfl_xor(acc.w, 32);
    if (half == 0) {
        float4 b4 = ((const float4*)bias)[l32];
        float ra = fmaxf(fmaf(acc.x, nd, b4.x), 0.f) * ns;
        float rb = fmaxf(fmaf(acc.y, nd, b4.y), 0.f) * ns;
        float rc = fmaxf(fmaf(acc.z, nd, b4.z), 0.f) * ns;
        float rd = fmaxf(fmaf(acc.w, nd, b4.w), 0.f) * ns;
        __half2 h0 = __floats2half2_rn(ra, rb);
        __half2 h1v = __floats2half2_rn(rc, rd);
        uint2 u;
        u.x = *(unsigned int*)&h0;
        u.y = *(unsigned int*)&h1v;
        ((uint2*)h1)[(size_t)v * 32 + l32] = u;
    }
}

// ---------------- layer-2 gather (date list), adaptive window like gather1 ------------------
__global__ __launch_bounds__(256) void gather2_list_kernel(
    const __half* __restrict__ h, const int* __restrict__ deg_in,
    const int2* __restrict__ ell, const float* __restrict__ norm_dst,
    const int* __restrict__ list, const int* __restrict__ cnt,
    float* __restrict__ out) {
    int wave = (blockIdx.x * 256 + threadIdx.x) >> 6;
    int lane = threadIdx.x & 63;
    if (wave >= min(*cnt, MAXDATE)) return;
    int v = __builtin_amdgcn_readfirstlane(list[wave]);
    int half = lane >> 5;
    int l32  = lane & 31;
    const int2* row = ell + (size_t)v * SLOTS;
    int m = min(__builtin_amdgcn_readfirstlane(deg_in[v]), SLOTS);
    float4 acc = make_float4(0.f, 0.f, 0.f, 0.f);

    if (m <= 16) {
        int4 q[8];
        #pragma unroll
        for (int i = 0; i < 8; ++i) q[i] = *(const int4*)&row[2 * i];
        float2 r[8];
        float w[8];
        #pragma unroll
        for (int i = 0; i < 8; ++i) {
            bool ok = (2 * i + half) < m;
            int s = ok ? (half ? q[i].z : q[i].x) : 0;
            w[i] = ok ? __int_as_float(half ? q[i].w : q[i].y) : 0.f;
            r[i] = ((const float2*)h)[(size_t)s * 32 + l32];
        }
        #pragma unroll
        for (int i = 0; i < 8; ++i) {
            float2 a01 = __half22float2(*(const __half2*)&r[i].x);
            float2 a23 = __half22float2(*(const __half2*)&r[i].y);
            acc.x = fmaf(w[i], a01.x, acc.x);
            acc.y = fmaf(w[i], a01.y, acc.y);
            acc.z = fmaf(w[i], a23.x, acc.z);
            acc.w = fmaf(w[i], a23.y, acc.w);
        }
    } else {
        int4 q[16];
        #pragma unroll
        for (int i = 0; i < 16; ++i) q[i] = *(const int4*)&row[2 * i];
        float2 r[16];
        float w[16];
        #pragma unroll
        for (int i = 0; i < 16; ++i) {
            bool ok = (2 * i + half) < m;
            int s = ok ? (half ? q[i].z : q[i].x) : 0;
            w[i] = ok ? __int_as_float(half ? q[i].w : q[i].y) : 0.f;
            r[i] = ((const float2*)h)[(size_t)s * 32 + l32];
        }
        #pragma unroll
        for (int i = 0; i < 16; ++i) {
            float2 a01 = __half22float2(*(const __half2*)&r[i].x);
            float2 a23 = __half22float2(*(const __half2*)&r[i].y);
            acc.x = fmaf(w[i], a01.x, acc.x);
            acc.y = fmaf(w[i], a01.y, acc.y);
            acc.z = fmaf(w[i], a23.x, acc.z);
            acc.w = fmaf(w[i], a23.y, acc.w);
        }
        if (m > 32) {
            for (int e = 32; e < m; e += 4) {
                int4 qa = *(const int4*)&row[e];
                int4 qb = *(const int4*)&row[e + 2];
                int2 p0 = half ? make_int2(qa.z, qa.w) : make_int2(qa.x, qa.y);
                int2 p1 = half ? make_int2(qb.z, qb.w) : make_int2(qb.x, qb.y);
                bool v0 = (e + half) < m;
                bool v1 = (e + 2 + half) < m;
                int s0 = v0 ? p0.x : 0;
                int s1 = v1 ? p1.x : 0;
                float2 raw0 = ((const float2*)h)[(size_t)s0 * 32 + l32];
                float2 raw1 = ((const float2*)h)[(size_t)s1 * 32 + l32];
                float w0 = v0 ? __int_as_float(p0.y) : 0.f;
                float w1 = v1 ? __int_as_float(p1.y) : 0.f;
                float2 a01 = __half22float2(*(const __half2*)&raw0.x);
                float2 a23 = __half22float2(*(const __half2*)&raw0.y);
                float2 b01 = __half22float2(*(const __half2*)&raw1.x);
                float2 b23 = __half22float2(*(const __half2*)&raw1.y);
                acc.x = fmaf(w0, a01.x, acc.x); acc.x = fmaf(w1, b01.x, acc.x);
                acc.y = fmaf(w0, a01.y, acc.y); acc.y = fmaf(w1, b01.y, acc.y);
                acc.z = fmaf(w0, a23.x, acc.z); acc.z = fmaf(w1, b23.x, acc.z);
                acc.w = fmaf(w0, a23.y, acc.w); acc.w = fmaf(w1, b23.y, acc.w);
            }
        }
    }
    acc.x += __shfl_xor(acc.x, 32);
    acc.y += __shfl_xor(acc.y, 32);
    acc.z += __shfl_xor(acc.z, 32);
    acc.w += __shfl_xor(acc.w, 32);
    if (half == 0) {
        float nd = norm_dst[v];
        ((float4*)(out + (size_t)wave * D))[l32] =
            make_float4(acc.x * nd, acc.y * nd, acc.z * nd, acc.w * nd);
    }
}

// ---------------- GEMM + bias + relu + fused sum-pool, W1-stationary in LDS -----------------
__global__ __launch_bounds__(512) void gemm_pool_kernel(
    const float* __restrict__ X, const float* __restrict__ W,
    const float* __restrict__ bias, const int* __restrict__ cnt,
    float* __restrict__ pooled) {
    __shared__ float wlds[D * D];           // 64 KB
    __shared__ float rows[PWAVES][GT * D];  // 64 KB
    int tid  = threadIdx.x;
    int lane = tid & 63;
    int wib  = tid >> 6;

    const float4* W4 = (const float4*)W;
    for (int i = tid; i < (D * D) / 4; i += 512)
        *(float4*)&wlds[i * 4] = W4[i];
    __syncthreads();

    int m = min(*cnt, MAXDATE);
    int ntiles = (m + GT - 1) / GT;
    float2 bb = ((const float2*)bias)[lane];
    float psx = 0.f, psy = 0.f;
    bool any = false;
    float* rw = rows[wib];
    const float2* X2 = (const float2*)X;

    for (int tile = blockIdx.x * PWAVES + wib; tile < ntiles; tile += gridDim.x * PWAVES) {
        int t0 = tile * GT;
        any = true;
        #pragma unroll
        for (int t = 0; t < GT; ++t) {
            int i = t0 + t;
            float2 r = (i < m) ? X2[(size_t)i * 64 + lane] : make_float2(0.f, 0.f);
            *(float2*)&rw[t * D + 2 * lane] = r;
        }
        __builtin_amdgcn_wave_barrier();

        float2 acc[GT];
        #pragma unroll
        for (int t = 0; t < GT; ++t) acc[t] = make_float2(0.f, 0.f);

        for (int k = 0; k < D; k += 4) {
            float2 w0 = *(const float2*)&wlds[(k + 0) * D + 2 * lane];
            float2 w1 = *(const float2*)&wlds[(k + 1) * D + 2 * lane];
            float2 w2 = *(const float2*)&wlds[(k + 2) * D + 2 * lane];
            float2 w3 = *(const float2*)&wlds[(k + 3) * D + 2 * lane];
            #pragma unroll
            for (int t = 0; t < GT; ++t) {
                float4 r = *(const float4*)&rw[t * D + k];
                acc[t].x = fmaf(r.x, w0.x, acc[t].x); acc[t].y = fmaf(r.x, w0.y, acc[t].y);
                acc[t].x = fmaf(r.y, w1.x, acc[t].x); acc[t].y = fmaf(r.y, w1.y, acc[t].y);
                acc[t].x = fmaf(r.z, w2.x, acc[t].x); acc[t].y = fmaf(r.z, w2.y, acc[t].y);
                acc[t].x = fmaf(r.w, w3.x, acc[t].x); acc[t].y = fmaf(r.w, w3.y, acc[t].y);
            }
        }

        #pragma unroll
        for (int t = 0; t < GT; ++t) {
            if (t0 + t < m) {
                psx += fmaxf(acc[t].x + bb.x, 0.f);
                psy += fmaxf(acc[t].y + bb.y, 0.f);
            }
        }
        __builtin_amdgcn_wave_barrier();   // rows slab reused next grid-stride iter
    }

    if (any) {
        atomicAdd(&pooled[2 * lane + 0], psx);
        atomicAdd(&pooled[2 * lane + 1], psy);
    }
}

// ---------------- tiny MLP head ----------------
__global__ void mlp_kernel(const float* __restrict__ pooled, const int* __restrict__ cnt,
                           const float* __restrict__ w1, const float* __restrict__ b1,
                           const float* __restrict__ w2, const float* __restrict__ b2,
                           float* __restrict__ out) {
    __shared__ float hid[8];
    int t = threadIdx.x;
    float inv = 1.0f / (float)(*cnt);
    if (t < 8) {
        float a = b1[t];
        for (int k = 0; k < 128; ++k) a = fmaf(pooled[k] * inv, w1[k * 8 + t], a);
        hid[t] = fmaxf(a, 0.f);
    }
    __syncthreads();
    if (t < 16) {
        float a = b2[t];
        for (int j = 0; j < 8; ++j) a = fmaf(hid[j], w2[j * 16 + t], a);
        out[t] = a;
    }
}

extern "C" void kernel_launch(void* const* d_in, const int* in_sizes, int n_in,
                              void* d_out, int out_size, void* d_ws, size_t ws_size,
                              hipStream_t stream) {
    const float* feature   = (const float*)d_in[0];
    const float* ew        = (const float*)d_in[1];
    const int*   src       = (const int*)d_in[2];
    const int*   dst       = (const int*)d_in[3];
    const int*   node_type = (const int*)d_in[4];
    const float* W0        = (const float*)d_in[5];
    const float* b0        = (const float*)d_in[6];
    const float* W1        = (const float*)d_in[7];
    const float* b1        = (const float*)d_in[8];
    const float* mw1       = (const float*)d_in[9];
    const float* mb1       = (const float*)d_in[10];
    const float* mw2       = (const float*)d_in[11];
    const float* mb2       = (const float*)d_in[12];
    float* out = (float*)d_out;

    const int n = in_sizes[0] / D;   // 100000
    const int E = in_sizes[1];       // 1600000
    const int NBK = (n + 255) >> 8;  // 391

    // ---- workspace carve-up (aligned to 256B), ~99 MB ----
    char* ws = (char*)d_ws;
    size_t off = 0;
    auto alloc = [&](size_t bytes) -> void* {
        void* p = ws + off;
        off = (off + bytes + 255) & ~(size_t)255;
        return p;
    };
    int*           cursorAB = (int*)alloc(2 * MAXB * 4);
    int*           deg_in   = (int*)alloc((size_t)n * 4);
    int*           deg_out  = (int*)alloc((size_t)n * 4);
    float*         norm_src = (float*)alloc((size_t)n * 4);
    float*         norm_dst = (float*)alloc((size_t)n * 4);
    int*           list     = (int*)alloc((size_t)n * 4);
    int*           list2    = (int*)alloc((size_t)n * 4);
    unsigned char* flag     = (unsigned char*)alloc((size_t)n);
    int2*          ell      = (int2*)alloc(((size_t)n * SLOTS + 8) * 8);  // 38.4 MB
    int2*          ebuf     = (int2*)alloc((size_t)NBK * CAPE * 8);       // 16 MB
    unsigned char* sbuf     = (unsigned char*)alloc((size_t)NBK * CAPE);  // 2 MB (bytes)
    unsigned char* P8       = (unsigned char*)alloc((size_t)n * D);       // 12.8 MB (fp8)
    __half*        h1       = (__half*)alloc((size_t)n * D * 2);          // 25.6 MB
    _Float16*      wp       = (_Float16*)alloc(2 * WPN * 2);              // 64 KB (hi+lo)
    float*         pooled   = (float*)alloc(D * 4);
    int*           cnt      = (int*)alloc(256);
    float*         agg      = (float*)ebuf;   // 4 MB, ebuf dead after build_count

    int* cursorA = cursorAB;
    int* cursorB = cursorAB + MAXB;
    int* cnt2    = cnt + 1;

    const int TB = 256;
    int pblk = (E + EPB - 1) / EPB;
    int nblk = (n + TB - 1) / TB;

    wpack_kernel<<<16, TB, 0, stream>>>(W0, wp, cursorAB, pooled, cnt);
    partition_kernel<<<pblk, PTB, 0, stream>>>(src, dst, ew, cursorA, cursorB, ebuf, sbuf, E, NBK);
    build_count_kernel<<<2 * NBK, TB, 0, stream>>>(ebuf, cursorA, sbuf, cursorB,
                                                   ell, deg_in, deg_out, n, NBK);
    norm_flag_kernel<<<nblk, TB, 0, stream>>>(deg_out, deg_in, node_type,
                                              norm_src, norm_dst, list, cnt, flag, n);
    mark_kernel<<<(MAXDATE * 64) / TB, TB, 0, stream>>>(list, cnt, ell, deg_in, flag);
    compact_kernel<<<nblk, TB, 0, stream>>>(flag, deg_in, list2, cnt2, n);

    // P8 = fp8(( norm_src . X ) @ W0) via MFMA (wp LDS-staged, 512-thread blocks)
    gemm_mfma_kernel<<<(n + 127) / 128, 512, 0, stream>>>(feature, norm_src, wp, P8, n);

    // layer 1 aggregation over the compact flagged list + epilogue
    gather1_kernel<<<(n * 64 + TB - 1) / TB, TB, 0, stream>>>(
        P8, ell, norm_src, norm_dst, b0, list2, cnt2, h1);

    // layer 2: date nodes only
    gather2_list_kernel<<<(MAXDATE * 64) / TB, TB, 0, stream>>>(
        h1, deg_in, ell, norm_dst, list, cnt, agg);
    gemm_pool_kernel<<<64, 512, 0, stream>>>(agg, W1, b1, cnt, pooled);

    mlp_kernel<<<1, 64, 0, stream>>>(pooled, cnt, mw1, mb1, mw2, mb2, out);
}